// Round 5
// baseline (251.227 us; speedup 1.0000x reference)
//
#include <hip/hip_runtime.h>
#include <hip/hip_bf16.h>

typedef __attribute__((ext_vector_type(8))) short short8;
typedef __attribute__((ext_vector_type(4))) short s4v;
typedef __attribute__((ext_vector_type(2))) int   int2v;
typedef __attribute__((ext_vector_type(4))) int   int4v;
typedef __attribute__((ext_vector_type(4))) float floatx4;

#define MFMA16(A,B,C) __builtin_amdgcn_mfma_f32_16x16x32_bf16(A,B,C,0,0,0)

__device__ __forceinline__ short bf16bits(float x) {
    __hip_bfloat16 h = __float2bfloat16(x);
    return *(short*)&h;
}
__device__ __forceinline__ short8 cvt8(const float* p) {
    floatx4 a = *(const floatx4*)p;
    floatx4 b = *(const floatx4*)(p + 4);
    short8 r;
    r[0]=bf16bits(a.x); r[1]=bf16bits(a.y); r[2]=bf16bits(a.z); r[3]=bf16bits(a.w);
    r[4]=bf16bits(b.x); r[5]=bf16bits(b.y); r[6]=bf16bits(b.z); r[7]=bf16bits(b.w);
    return r;
}
// scaled variant for Q: folds 1/sqrt(d) * log2(e) so softmax is a bare v_exp_f32
__device__ __forceinline__ short8 cvt8s(const float* p) {
    constexpr float SCL2 = 0.125f * 1.44269504088896f;
    floatx4 a = *(const floatx4*)p;
    floatx4 b = *(const floatx4*)(p + 4);
    a *= SCL2; b *= SCL2;
    short8 r;
    r[0]=bf16bits(a.x); r[1]=bf16bits(a.y); r[2]=bf16bits(a.z); r[3]=bf16bits(a.w);
    r[4]=bf16bits(b.x); r[5]=bf16bits(b.y); r[6]=bf16bits(b.z); r[7]=bf16bits(b.w);
    return r;
}
// hardware packed f32->bf16 (RNE, identical rounding to __float2bfloat16)
__device__ __forceinline__ int pk2(float lo, float hi) {
    int r;
    asm("v_cvt_pk_bf16_f32 %0, %1, %2" : "=v"(r) : "v"(lo), "v"(hi));
    return r;
}
// direct global->LDS DMA, 16B/lane; LDS dest is wave-uniform base + lane*16
__device__ __forceinline__ void g2l16(const short* g, short* l) {
    __builtin_amdgcn_global_load_lds(
        (const __attribute__((address_space(1))) void*)g,
        (__attribute__((address_space(3))) void*)l, 16, 0, 0);
}

// ---- prologue (fused): V -> VT [h][d][s] bf16, and K -> K16 bf16 row-major ----
__global__ __launch_bounds__(256) void prep(const float* __restrict__ V,
                                            short* __restrict__ VT,
                                            const float* __restrict__ K,
                                            short* __restrict__ K16, int doK)
{
    __shared__ short tile[64 * 65];
    const int t  = threadIdx.x;
    const int h  = blockIdx.x >> 6;
    const int s0 = (blockIdx.x & 63) << 6;
    const float* src = V + ((size_t)h * 4096 + s0) * 64;
    const int r = t >> 4, dq = (t & 15) * 4;
#pragma unroll
    for (int pass = 0; pass < 4; ++pass) {
        const int s = pass * 16 + r;
        floatx4 f = *(const floatx4*)(src + s * 64 + dq);
        short* w = tile + s * 65 + dq;
        w[0] = bf16bits(f.x); w[1] = bf16bits(f.y);
        w[2] = bf16bits(f.z); w[3] = bf16bits(f.w);
    }
    __syncthreads();
    const int d = t >> 2, sc = (t & 3) * 16;
    short8 a, b;
#pragma unroll
    for (int j = 0; j < 8; ++j) a[j] = tile[(sc + j) * 65 + d];
#pragma unroll
    for (int j = 0; j < 8; ++j) b[j] = tile[(sc + 8 + j) * 65 + d];
    short* dst = VT + ((size_t)h * 64 + d) * 4096 + s0 + sc;
    *(short8*)dst       = a;
    *(short8*)(dst + 8) = b;
    if (doK) {
        const size_t base = (size_t)blockIdx.x * 4096 + (size_t)t * 16;
        *(short8*)(K16 + base)     = cvt8(K + base);
        *(short8*)(K16 + base + 8) = cvt8(K + base + 8);
    }
}

// ---- main: 2 waves x 32q (2 groups of 16), 64-key tiles, 1024 blocks ----
// Each kf/vf LDS read feeds TWO MFMAs (q-groups A,B): 16 b128 reads -> 36 MFMA
// per wave-tile (R4: 20 LDS -> 18 MFMA). K/V staged by global_load_lds into a
// double buffer (1 barrier/tile); P stays in registers via permlane swaps.
template<bool KB16>
__global__ __launch_bounds__(128, 2)
void attn_fast(const float* __restrict__ Qg, const float* __restrict__ Kg,
               const short* __restrict__ K16g, const short* __restrict__ VTg,
               float* __restrict__ Og)
{
    constexpr int S = 4096, D = 64;

    __shared__ __align__(16) short lK[8192];   // 2 x (64 keys x 64 d), swizzled
    __shared__ __align__(16) short lV[8192];   // 2 x (64 d x 64 keys), swizzled

    const int tid = threadIdx.x;
    const int wv  = tid >> 6;        // 0..1
    const int ln  = tid & 63;
    const int ll  = ln & 15;
    const int qd  = ln >> 4;

    // balanced qblk mapping: per-CU sets {63-x, 32+x, 31-x, x}
    const int c = blockIdx.x & 255;
    const int s = blockIdx.x >> 8;
    const int h = c & 15;
    const int x = c >> 4;
    const int qblk = (s == 0) ? (63 - x) : (s == 1) ? (32 + x) : (s == 2) ? (31 - x) : x;
    const int qb   = qblk << 6;
    const int qrow = qb + wv * 32;            // wave owns 32 q-rows

    const float* Qh  = Qg  + (size_t)h * S * D;
    const float* Kf  = Kg  + (size_t)h * S * D;
    const short* K16 = K16g + (size_t)h * S * D;
    const short* Vt  = VTg + (size_t)h * 64 * S;

    // Q fragments for both 16-row groups, pre-scaled
    short8 qA0, qA1, qB0, qB1;
    {
        const float* qp = Qh + (qrow + ll) * D + qd * 8;
        qA0 = cvt8s(qp);       qA1 = cvt8s(qp + 32);
        const float* qp2 = qp + 16 * D;
        qB0 = cvt8s(qp2);      qB1 = cvt8s(qp2 + 32);
    }

    floatx4 oA[4], oB[4], olA, olB;
#pragma unroll
    for (int dt = 0; dt < 4; ++dt) { oA[dt] = (floatx4){0.f,0.f,0.f,0.f}; oB[dt] = oA[dt]; }
    olA = (floatx4){0.f,0.f,0.f,0.f};
    olB = olA;

    short8 ones;
#pragma unroll
    for (int j = 0; j < 8; ++j) ones[j] = (short)0x3F80;  // bf16 1.0

    // ---- staging via global_load_lds: linear LDS dest, swizzle-inverted source.
    // wave w, instr j (0..3) covers LDS short8-slots [(w*4+j)*64, +64).
    // Decode (HW-verified in R3): slot -> hh=slot>>8, bb=(slot>>6)&3, sw=slot&63,
    //   ko=(sw>>4)&3; kkey=hh*32+(bb>>1)*16+((sw^(ko*5))&15); kd8=((bb&1)<<2)|ko
    //   vd=bb*16+((sw^(ko*5))&15); vOff=vd*S+hh*32+ko*8
    int kOf0, kOf1, kOf2, kOf3, vOf0, vOf1, vOf2, vOf3;
    const float *kFp0, *kFp1, *kFp2, *kFp3;    // fp32 K source (KB16=false path)
#define DECODE_SLOT(J, KOF, VOF, KFP) {                                        \
        const int slot = (wv * 4 + (J)) * 64 + ln;                             \
        const int hh = slot >> 8, bb = (slot >> 6) & 3, sw = slot & 63;        \
        const int ko = (sw >> 4) & 3;                                          \
        const int kkey = hh * 32 + (bb >> 1) * 16 + ((sw ^ (ko * 5)) & 15);    \
        const int kd8  = ((bb & 1) << 2) | ko;                                 \
        const int vd   = bb * 16 + ((sw ^ (ko * 5)) & 15);                     \
        KOF = kkey * 64 + kd8 * 8;                                             \
        VOF = vd * S + hh * 32 + ko * 8;                                       \
        KFP = Kf + (size_t)kkey * D + kd8 * 8;                                 \
    }
    DECODE_SLOT(0, kOf0, vOf0, kFp0)
    DECODE_SLOT(1, kOf1, vOf1, kFp1)
    DECODE_SLOT(2, kOf2, vOf2, kFp2)
    DECODE_SLOT(3, kOf3, vOf3, kFp3)
#undef DECODE_SLOT
    const int d0 = wv * 2048 + 0 * 512;   // LDS short-offset of this wave's chunks
    const int d1 = wv * 2048 + 1 * 512;
    const int d2 = wv * 2048 + 2 * 512;
    const int d3 = wv * 2048 + 3 * 512;

    // fragment read block (lK / lV) — wv-independent; identical across waves
    const int rblk = ((ll | (qd << 4)) ^ (qd * 5));

    const int kv_end = qb + 64;
    const int wv_end = qrow + 32;

    // softmax + in-register P->A-fragment transpose (no LDS), per 16-q group:
    // P32(w0,w2), P32(w1,w3), P16(w0,w2), P16(w1,w3)  [HW-verified in R4]
    auto mkpf = [&](floatx4 sc0, floatx4 sc1, int qgrp, int kvh) -> short8 {
        float p0[4], p1[4];
#pragma unroll
        for (int r = 0; r < 4; ++r) { p0[r] = exp2f(sc0[r]); p1[r] = exp2f(sc1[r]); }
        if (kvh + 31 > qgrp) {                 // diagonal tiles only
            const int qg = qgrp + ll;
            const int k0 = kvh + qd * 4, k1 = k0 + 16;
#pragma unroll
            for (int r = 0; r < 4; ++r) {
                if (k0 + r > qg) p0[r] = 0.f;
                if (k1 + r > qg) p1[r] = 0.f;
            }
        }
        int w0 = pk2(p0[0], p0[1]);
        int w1 = pk2(p0[2], p0[3]);
        int w2 = pk2(p1[0], p1[1]);
        int w3 = pk2(p1[2], p1[3]);
        asm("v_permlane32_swap_b32 %0, %1" : "+v"(w0), "+v"(w2));
        asm("v_permlane32_swap_b32 %0, %1" : "+v"(w1), "+v"(w3));
        asm("v_permlane16_swap_b32 %0, %1" : "+v"(w0), "+v"(w2));
        asm("v_permlane16_swap_b32 %0, %1" : "+v"(w1), "+v"(w3));
        int4v pv = {w0, w1, w2, w3};
        return *(short8*)&pv;
    };

    // ---- prologue: stage tile 0 into buffer 0
    short8 kp0, kp1, kp2, kp3;                 // K prefetch regs (false path only)
    g2l16(Vt + vOf0, lV + d0);
    g2l16(Vt + vOf1, lV + d1);
    g2l16(Vt + vOf2, lV + d2);
    g2l16(Vt + vOf3, lV + d3);
    if (KB16) {
        g2l16(K16 + kOf0, lK + d0);
        g2l16(K16 + kOf1, lK + d1);
        g2l16(K16 + kOf2, lK + d2);
        g2l16(K16 + kOf3, lK + d3);
    } else {
        *(short8*)(lK + d0 + ln * 8) = cvt8(kFp0);
        *(short8*)(lK + d1 + ln * 8) = cvt8(kFp1);
        *(short8*)(lK + d2 + ln * 8) = cvt8(kFp2);
        *(short8*)(lK + d3 + ln * 8) = cvt8(kFp3);
        kp0 = cvt8(kFp0 + 64 * D); kp1 = cvt8(kFp1 + 64 * D);
        kp2 = cvt8(kFp2 + 64 * D); kp3 = cvt8(kFp3 + 64 * D);
    }

    int bo = 0;
    for (int kv = 0; kv < kv_end; kv += 64) {
        // single barrier per tile: drains prev-iter DMA (vmcnt+lgkm) + syncs waves
        __syncthreads();
        const int nbo = bo ^ 4096;
        if (kv + 64 < kv_end) {            // stage next tile into other buffer
            const short* Vs = Vt + (kv + 64);
            g2l16(Vs + vOf0, lV + nbo + d0);
            g2l16(Vs + vOf1, lV + nbo + d1);
            g2l16(Vs + vOf2, lV + nbo + d2);
            g2l16(Vs + vOf3, lV + nbo + d3);
            if (KB16) {
                const short* Ks = K16 + (size_t)(kv + 64) * 64;
                g2l16(Ks + kOf0, lK + nbo + d0);
                g2l16(Ks + kOf1, lK + nbo + d1);
                g2l16(Ks + kOf2, lK + nbo + d2);
                g2l16(Ks + kOf3, lK + nbo + d3);
            } else {
                *(short8*)(lK + nbo + d0 + ln * 8) = kp0;
                *(short8*)(lK + nbo + d1 + ln * 8) = kp1;
                *(short8*)(lK + nbo + d2 + ln * 8) = kp2;
                *(short8*)(lK + nbo + d3 + ln * 8) = kp3;
                if (kv + 128 < kv_end) {
                    const int adv = (kv + 128) * D;
                    kp0 = cvt8(kFp0 + adv); kp1 = cvt8(kFp1 + adv);
                    kp2 = cvt8(kFp2 + adv); kp3 = cvt8(kFp3 + adv);
                }
            }
        }

        {
            const bool h1 = (kv + 32 < wv_end);
            const short* Kb = lK + bo;
            const short* Vb = lV + bo;
            // S^T = K Q^T; each kf feeds both q-groups (2x reuse)
            floatx4 zz = (floatx4){0.f,0.f,0.f,0.f};
            floatx4 sA0=zz, sA1=zz, sA2=zz, sA3=zz;
            floatx4 sB0=zz, sB1=zz, sB2=zz, sB3=zz;
            short8 kf;
            __builtin_amdgcn_s_setprio(1);
            kf = ((const short8*)(Kb +    0))[rblk]; sA0 = MFMA16(kf, qA0, sA0); sB0 = MFMA16(kf, qB0, sB0);
            kf = ((const short8*)(Kb +  512))[rblk]; sA0 = MFMA16(kf, qA1, sA0); sB0 = MFMA16(kf, qB1, sB0);
            kf = ((const short8*)(Kb + 1024))[rblk]; sA1 = MFMA16(kf, qA0, sA1); sB1 = MFMA16(kf, qB0, sB1);
            kf = ((const short8*)(Kb + 1536))[rblk]; sA1 = MFMA16(kf, qA1, sA1); sB1 = MFMA16(kf, qB1, sB1);
            if (h1) {
                kf = ((const short8*)(Kb + 2048))[rblk]; sA2 = MFMA16(kf, qA0, sA2); sB2 = MFMA16(kf, qB0, sB2);
                kf = ((const short8*)(Kb + 2560))[rblk]; sA2 = MFMA16(kf, qA1, sA2); sB2 = MFMA16(kf, qB1, sB2);
                kf = ((const short8*)(Kb + 3072))[rblk]; sA3 = MFMA16(kf, qA0, sA3); sB3 = MFMA16(kf, qB0, sB3);
                kf = ((const short8*)(Kb + 3584))[rblk]; sA3 = MFMA16(kf, qA1, sA3); sB3 = MFMA16(kf, qB1, sB3);
            }
            __builtin_amdgcn_s_setprio(0);

            // half 0: softmax -> in-reg P fragments -> PV (vf shared by groups)
            short8 pfA = mkpf(sA0, sA1, qrow,      kv);
            short8 pfB = mkpf(sB0, sB1, qrow + 16, kv);
            __builtin_amdgcn_s_setprio(1);
#pragma unroll
            for (int dt = 0; dt < 4; ++dt) {
                short8 vf = ((const short8*)(Vb + dt * 512))[rblk];
                oA[dt] = MFMA16(pfA, vf, oA[dt]);
                oB[dt] = MFMA16(pfB, vf, oB[dt]);
            }
            olA = MFMA16(pfA, ones, olA);
            olB = MFMA16(pfB, ones, olB);
            __builtin_amdgcn_s_setprio(0);
            if (h1) {
                short8 pfA1 = mkpf(sA2, sA3, qrow,      kv + 32);
                short8 pfB1 = mkpf(sB2, sB3, qrow + 16, kv + 32);
                __builtin_amdgcn_s_setprio(1);
#pragma unroll
                for (int dt = 0; dt < 4; ++dt) {
                    short8 vf = ((const short8*)(Vb + 2048 + dt * 512))[rblk];
                    oA[dt] = MFMA16(pfA1, vf, oA[dt]);
                    oB[dt] = MFMA16(pfB1, vf, oB[dt]);
                }
                olA = MFMA16(pfA1, ones, olA);
                olB = MFMA16(pfB1, ones, olB);
                __builtin_amdgcn_s_setprio(0);
            }
        }
        bo = nbo;
    }

#pragma unroll
    for (int r = 0; r < 4; ++r) {
        const float rl = 1.f / fmaxf(olA[r], 1e-37f);
        const int q = qrow + qd * 4 + r;
        float* op = Og + ((size_t)h * S + q) * D + ll;
#pragma unroll
        for (int dt = 0; dt < 4; ++dt)
            op[dt * 16] = oA[dt][r] * rl;
    }
#pragma unroll
    for (int r = 0; r < 4; ++r) {
        const float rl = 1.f / fmaxf(olB[r], 1e-37f);
        const int q = qrow + 16 + qd * 4 + r;
        float* op = Og + ((size_t)h * S + q) * D + ll;
#pragma unroll
        for (int dt = 0; dt < 4; ++dt)
            op[dt * 16] = oB[dt][r] * rl;
    }
}

// ---- fallback (round-3 verified kernel, no workspace needed) ----
__global__ __launch_bounds__(256, 4)
void attn_legacy(const float* __restrict__ Qg, const float* __restrict__ Kg,
                 const float* __restrict__ Vg, float* __restrict__ Og)
{
    constexpr int S = 4096, D = 64;
    constexpr float SCL2 = 0.125f * 1.44269504088896f;
    constexpr float NEG  = -1.0e30f;
    __shared__ __align__(16) short lK[2048];
    __shared__ __align__(16) short lV[2048];
    __shared__ __align__(16) short lP[2048];
    const int tid = threadIdx.x, wv = tid >> 6, ln = tid & 63, ll = ln & 15, qd = ln >> 4;
    const int bid = blockIdx.x, h = bid & 15, qblk = 63 - (bid >> 4), qb = qblk << 6;
    const float* Qh = Qg + (size_t)h * S * D;
    const float* Kh = Kg + (size_t)h * S * D;
    const float* Vh = Vg + (size_t)h * S * D;
    const int qrow = qb + wv * 16;
    short8 qf0, qf1;
    { const float* qp = Qh + (qrow + ll) * D + qd * 8; qf0 = cvt8(qp); qf1 = cvt8(qp + 32); }
    floatx4 o[4]; float mi[4], li[4];
#pragma unroll
    for (int dt = 0; dt < 4; ++dt) o[dt] = (floatx4){0.f,0.f,0.f,0.f};
#pragma unroll
    for (int r = 0; r < 4; ++r) { mi[r] = NEG; li[r] = 0.f; }
    const int k_st = tid >> 3, dbase = (tid & 7) * 8;
    const int sq = (dbase >> 3) & 3, sks = dbase >> 5;
    const int kw_slot = (((k_st >> 4) * 2 + sks) * 64)
                      + (((sq << 4) | (k_st & 15)) ^ (sq | (sks << 2)));
    const int kr0 = ln ^ qd, kr1 = ln ^ (qd | 4), vbit3 = (ln >> 3) & 1;
    const int kv_end = qb + 64, wv_end = qrow + 16;
    for (int kv = 0; kv < kv_end; kv += 32) {
        __syncthreads();
        {
            short8 kval = cvt8(Kh + (kv + k_st) * D + dbase);
            ((short8*)lK)[kw_slot] = kval;
            short8 vval = cvt8(Vh + (kv + k_st) * D + dbase);
            const int vq = (k_st >> 3) << 4, vj = k_st & 7;
#pragma unroll
            for (int i = 0; i < 8; ++i) {
                int d = dbase + i, dt = d >> 4, l2 = d & 15;
                int lp = (vq | l2) ^ (((l2 >> 3) & 1) | (dt << 1));
                lV[dt * 512 + lp * 8 + vj] = vval[i];
            }
        }
        __syncthreads();
        if (kv < wv_end) {
            floatx4 sc0 = (floatx4){0.f,0.f,0.f,0.f}, sc1 = sc0; short8 kf;
            kf = ((const short8*)lK)[0*64+kr0]; sc0 = MFMA16(qf0, kf, sc0);
            kf = ((const short8*)lK)[1*64+kr1]; sc0 = MFMA16(qf1, kf, sc0);
            kf = ((const short8*)lK)[2*64+kr0]; sc1 = MFMA16(qf0, kf, sc1);
            kf = ((const short8*)lK)[3*64+kr1]; sc1 = MFMA16(qf1, kf, sc1);
            float p0[4], p1[4]; const int qg = qrow + qd * 4;
#pragma unroll
            for (int r = 0; r < 4; ++r) { p0[r] = sc0[r]*SCL2; p1[r] = sc1[r]*SCL2; }
            if (kv + 31 > qrow) {
                const int k0 = kv + ll, k1 = kv + 16 + ll;
#pragma unroll
                for (int r = 0; r < 4; ++r) {
                    if (k0 > qg + r) p0[r] = NEG;
                    if (k1 > qg + r) p1[r] = NEG;
                }
            }
#pragma unroll
            for (int r = 0; r < 4; ++r) {
                float mx = fmaxf(p0[r], p1[r]);
                mx = fmaxf(mx, __shfl_xor(mx,1)); mx = fmaxf(mx, __shfl_xor(mx,2));
                mx = fmaxf(mx, __shfl_xor(mx,4)); mx = fmaxf(mx, __shfl_xor(mx,8));
                const float nm = fmaxf(mi[r], mx);
                const float a = exp2f(mi[r] - nm); mi[r] = nm;
                p0[r] = exp2f(p0[r] - nm); p1[r] = exp2f(p1[r] - nm);
                float ps = p0[r] + p1[r];
                ps += __shfl_xor(ps,1); ps += __shfl_xor(ps,2);
                ps += __shfl_xor(ps,4); ps += __shfl_xor(ps,8);
                li[r] = li[r] * a + ps;
#pragma unroll
                for (int dt = 0; dt < 4; ++dt) o[dt][r] *= a;
            }
            {
                const int pbase = wv * 512 + (ll & 7);
                const int dl0 = ((ll >> 3) << 4) + qd * 4;
#pragma unroll
                for (int r = 0; r < 4; ++r) {
                    lP[pbase + (dl0 + r) * 8]      = bf16bits(p0[r]);
                    lP[pbase + (dl0 + 32 + r) * 8] = bf16bits(p1[r]);
                }
            }
            __threadfence_block();
            short8 pf = ((const short8*)lP)[wv * 64 + ln];
#pragma unroll
            for (int dt = 0; dt < 4; ++dt) {
                short8 vf = ((const short8*)lV)[dt * 64 + (ln ^ (vbit3 | (dt << 1)))];
                o[dt] = MFMA16(pf, vf, o[dt]);
            }
        }
    }
#pragma unroll
    for (int r = 0; r < 4; ++r) {
        const float rl = 1.f / fmaxf(li[r], 1e-30f);
        const int q = qrow + qd * 4 + r;
        float* op = Og + ((size_t)h * S + q) * D + ll;
#pragma unroll
        for (int dt = 0; dt < 4; ++dt) op[dt * 16] = o[dt][r] * rl;
    }
}

extern "C" void kernel_launch(void* const* d_in, const int* in_sizes, int n_in,
                              void* d_out, int out_size, void* d_ws, size_t ws_size,
                              hipStream_t stream) {
    const float* Q = (const float*)d_in[0];
    const float* K = (const float*)d_in[1];
    const float* V = (const float*)d_in[2];
    float* O = (float*)d_out;
    const size_t elems  = (size_t)16 * 4096 * 64;
    const size_t oneBuf = elems * sizeof(short);          // 8.39 MB
    if (ws_size >= 2 * oneBuf) {
        short* VT  = (short*)d_ws;
        short* K16 = (short*)d_ws + elems;
        prep<<<dim3(1024), dim3(256), 0, stream>>>(V, VT, K, K16, 1);
        attn_fast<true><<<dim3(1024), dim3(128), 0, stream>>>(Q, K, K16, VT, O);
    } else if (ws_size >= oneBuf) {
        short* VT = (short*)d_ws;
        prep<<<dim3(1024), dim3(256), 0, stream>>>(V, VT, K, VT, 0);
        attn_fast<false><<<dim3(1024), dim3(128), 0, stream>>>(Q, K, nullptr, VT, O);
    } else {
        attn_legacy<<<dim3(1024), dim3(256), 0, stream>>>(Q, K, V, O);
    }
}